// Round 3
// baseline (1610.673 us; speedup 1.0000x reference)
//
#include <hip/hip_runtime.h>
#include <math.h>

#define CC 64
#define HW 4096
#define NB 4
#define NT 10
#define TR 4                     // output rows per block
#define CHUNK 16                 // input channels staged per chunk
#define LDSROW 68                // padded row width (col j = img col j-1)
#define ICSTRIDE (6*LDSROW)      // 408 floats per ic (6 rows)
#define BUFSZ (CHUNK*ICSTRIDE)   // 6528 floats per buffer

__device__ __forceinline__ float sigm(float x) { return 1.0f / (1.0f + expf(-x)); }

__device__ __forceinline__ void load_win6(const float* __restrict__ p, float (&w)[3][6]) {
#pragma unroll
    for (int dr = 0; dr < 3; ++dr) {
        float4 a  = *(const float4*)(p + dr * LDSROW);
        float2 e2 = *(const float2*)(p + dr * LDSROW + 4);
        w[dr][0] = a.x;  w[dr][1] = a.y;  w[dr][2] = a.z;
        w[dr][3] = a.w;  w[dr][4] = e2.x; w[dr][5] = e2.y;
    }
}

__device__ __forceinline__ void load_w9(const float* __restrict__ w, float (&d)[9]) {
#pragma unroll
    for (int i = 0; i < 9; ++i) d[i] = w[i];
}

// FMA from pre-loaded (register/SGPR) weights
__device__ __forceinline__ void fma36r(const float (&w)[9],
                                       const float (&win)[3][6], float (&a)[4]) {
#pragma unroll
    for (int pp = 0; pp < 4; ++pp) {
        float s = a[pp];
        s = fmaf(w[0], win[0][pp],   s);
        s = fmaf(w[1], win[0][pp+1], s);
        s = fmaf(w[2], win[0][pp+2], s);
        s = fmaf(w[3], win[1][pp],   s);
        s = fmaf(w[4], win[1][pp+1], s);
        s = fmaf(w[5], win[1][pp+2], s);
        s = fmaf(w[6], win[2][pp],   s);
        s = fmaf(w[7], win[2][pp+1], s);
        s = fmaf(w[8], win[2][pp+2], s);
        a[pp] = s;
    }
}

// FMA with direct weight loads (thr channel only — 1 wave of 32 uses it)
__device__ __forceinline__ void fma36(const float* __restrict__ w9,
                                      const float (&win)[3][6], float (&a)[4]) {
    float w[9];
    load_w9(w9, w);
    fma36r(w, win, a);
}

// ---------------------------------------------------------------------------
// Kernel A: rz = conv3x3(prev_y, w_rz) + b_rz (129 ch).
// 512 threads: tx16(4col) x t4(4row) x ocq8(4oc) -> 32 oc/block, 4 ocg blocks.
// thr (oc 128) folded into ocq==0 wave of ocg==0 blocks.
// Double-buffered LDS, reg-staged prefetch, 1 barrier per 16-ic chunk.
// ic loop: 2-deep software pipeline (win ping-pong + weight ping-pong) so the
// lgkmcnt drain (ds_read + s_load) never sits on the FMA critical path.
// ---------------------------------------------------------------------------
__global__ __launch_bounds__(512, 2) void convA_kernel(
    const float* __restrict__ prev_y,
    const float* __restrict__ xt_t,
    const float* __restrict__ w_rz,
    const float* __restrict__ b_rz,
    float* __restrict__ ws_u,
    float* __restrict__ ws_ry,
    float* __restrict__ ws_thr,
    int first)
{
    __shared__ float lds[2 * BUFSZ];
    const int tid = threadIdx.x;
    const int tx  = tid & 15;
    const int t4  = (tid >> 4) & 3;
    const int ocq = tid >> 6;                 // 0..7 == wave id
    const int b   = blockIdx.x;
    const int r0  = blockIdx.y * TR;
    const int ocg = blockIdx.z;               // 0..3
    const int oc0 = __builtin_amdgcn_readfirstlane(ocg * 32 + ocq * 4);
    const bool do_thr = (ocg == 0) && (ocq == 0);

    float acc[4][4];
#pragma unroll
    for (int o = 0; o < 4; ++o)
#pragma unroll
        for (int p = 0; p < 4; ++p) acc[o][p] = 0.f;
    float acct[4] = {0.f, 0.f, 0.f, 0.f};

    if (!first) {
        // staging mapping: 512 lanes = q16 x icl16 x rh2 (rows rh*3+0..2)
        const int q   = tid & 15;
        const int icl = (tid >> 4) & 15;
        const int rh  = tid >> 8;             // 0/1
        const float* gsrc = prev_y + ((size_t)b * CC + icl) * HW;
        float4 pf[3];

        // prologue: load + store chunk 0
#pragma unroll
        for (int j = 0; j < 3; ++j) {
            int sr = r0 - 1 + rh * 3 + j;
            pf[j] = make_float4(0.f, 0.f, 0.f, 0.f);
            if (sr >= 0 && sr < 64)
                pf[j] = *(const float4*)(gsrc + sr * 64 + 4 * q);
        }
        {
            float* dst = lds + icl * ICSTRIDE;
#pragma unroll
            for (int j = 0; j < 3; ++j) {
                int row = rh * 3 + j;
                float aw = __shfl_up(pf[j].w, 1, 16);
                if (q == 0) aw = 0.f;
                *(float4*)(dst + row * LDSROW + 4 * q) =
                    make_float4(aw, pf[j].x, pf[j].y, pf[j].z);
                if (q == 15)
                    *(float4*)(dst + row * LDSROW + 64) =
                        make_float4(pf[j].w, 0.f, 0.f, 0.f);
            }
        }
        __syncthreads();

#pragma unroll 1
        for (int ck = 0; ck < 4; ++ck) {
            // issue next chunk's global loads (hidden under compute)
            if (ck < 3) {
                const float* g = gsrc + (size_t)(ck + 1) * CHUNK * HW;
#pragma unroll
                for (int j = 0; j < 3; ++j) {
                    int sr = r0 - 1 + rh * 3 + j;
                    pf[j] = make_float4(0.f, 0.f, 0.f, 0.f);
                    if (sr >= 0 && sr < 64)
                        pf[j] = *(const float4*)(g + sr * 64 + 4 * q);
                }
            }
            const float* p  = lds + (ck & 1) * BUFSZ + t4 * LDSROW + 4 * tx;
            const float* wz = w_rz + ((size_t)oc0 * CC + ck * CHUNK) * 9;
            const float* wt = w_rz + ((size_t)128 * CC + ck * CHUNK) * 9;

            float winA[3][6], winB[3][6];
            float wA[4][9], wB[4][9];
            load_win6(p, winA);
#pragma unroll
            for (int o = 0; o < 4; ++o) load_w9(wz + o * CC * 9, wA[o]);

#pragma unroll 1
            for (int ic2 = 0; ic2 < CHUNK; ic2 += 2) {
                // stage B loads (ic2+1) issue before stage A compute
                load_win6(p + ICSTRIDE, winB);
#pragma unroll
                for (int o = 0; o < 4; ++o) load_w9(wz + 9 + o * CC * 9, wB[o]);

                fma36r(wA[0], winA, acc[0]);
                fma36r(wA[1], winA, acc[1]);
                fma36r(wA[2], winA, acc[2]);
                fma36r(wA[3], winA, acc[3]);
                if (do_thr) fma36(wt, winA, acct);

                if (ic2 + 2 < CHUNK) {        // stage A loads (ic2+2)
                    load_win6(p + 2 * ICSTRIDE, winA);
#pragma unroll
                    for (int o = 0; o < 4; ++o) load_w9(wz + 18 + o * CC * 9, wA[o]);
                }

                fma36r(wB[0], winB, acc[0]);
                fma36r(wB[1], winB, acc[1]);
                fma36r(wB[2], winB, acc[2]);
                fma36r(wB[3], winB, acc[3]);
                if (do_thr) fma36(wt + 9, winB, acct);

                p  += 2 * ICSTRIDE;
                wz += 18;
                wt += 18;
            }
            if (ck < 3) {
                float* dst = lds + ((ck + 1) & 1) * BUFSZ + icl * ICSTRIDE;
#pragma unroll
                for (int j = 0; j < 3; ++j) {
                    int row = rh * 3 + j;
                    float aw = __shfl_up(pf[j].w, 1, 16);
                    if (q == 0) aw = 0.f;
                    *(float4*)(dst + row * LDSROW + 4 * q) =
                        make_float4(aw, pf[j].x, pf[j].y, pf[j].z);
                    if (q == 15)
                        *(float4*)(dst + row * LDSROW + 64) =
                            make_float4(pf[j].w, 0.f, 0.f, 0.f);
                }
            }
            __syncthreads();
        }
    }

    // epilogue
    const int gr = r0 + t4;
    const size_t pix = (size_t)gr * 64 + 4 * tx;
    if (ocg < 2) {                            // z: update gate -> ws_u
#pragma unroll
        for (int o = 0; o < 4; ++o) {
            int oc = oc0 + o;
            float bias = b_rz[oc];
            const float4 x4 = *(const float4*)(xt_t + ((size_t)b * 192 + oc) * HW + pix);
            float4 outv;
            outv.x = sigm(acc[o][0] + bias + x4.x);
            outv.y = sigm(acc[o][1] + bias + x4.y);
            outv.z = sigm(acc[o][2] + bias + x4.z);
            outv.w = sigm(acc[o][3] + bias + x4.w);
            *(float4*)(ws_u + ((size_t)b * CC + oc) * HW + pix) = outv;
        }
    } else {                                  // r: ry = prev_y * reset_gate
#pragma unroll
        for (int o = 0; o < 4; ++o) {
            int oc = oc0 + o;
            int ch = oc - CC;
            float bias = b_rz[oc];
            const float4 x4 = *(const float4*)(xt_t + ((size_t)b * 192 + oc) * HW + pix);
            float4 py;
            if (first) { py = make_float4(0.f, 0.f, 0.f, 0.f); }
            else       { py = *(const float4*)(prev_y + ((size_t)b * CC + ch) * HW + pix); }
            float4 outv;
            outv.x = py.x * sigm(acc[o][0] + bias + x4.x);
            outv.y = py.y * sigm(acc[o][1] + bias + x4.y);
            outv.z = py.z * sigm(acc[o][2] + bias + x4.z);
            outv.w = py.w * sigm(acc[o][3] + bias + x4.w);
            *(float4*)(ws_ry + ((size_t)b * CC + ch) * HW + pix) = outv;
        }
    }
    if (do_thr) {
        float bias = b_rz[2 * CC];
        float4 outv;
        outv.x = sigm(acct[0] + bias);
        outv.y = sigm(acct[1] + bias);
        outv.z = sigm(acct[2] + bias);
        outv.w = sigm(acct[3] + bias);
        *(float4*)(ws_thr + (size_t)b * HW + pix) = outv;
    }
}

// ---------------------------------------------------------------------------
// Kernel B: f = conv3x3(ry, w_f) + b_f + xi_f ; fused GRU update + spike.
// 256 threads: tx16 x t4(4row) x ocq4(4oc) -> 16 oc/block, 4 ocg blocks.
// 1 block/CU -> 1 wave/SIMD: full 2-deep pipeline (win + weights) is the only
// latency cover available. __launch_bounds__(256,1) -> VGPR cap 512, no spill.
// ---------------------------------------------------------------------------
__global__ __launch_bounds__(256, 1) void convB_kernel(
    const float* __restrict__ ry,
    const float* __restrict__ xt_t,
    const float* __restrict__ w_f,
    const float* __restrict__ b_f,
    const float* __restrict__ ws_u,
    const float* __restrict__ ws_thr,
    float* __restrict__ ws_h,
    float* __restrict__ out_y,
    float* __restrict__ out_e,
    float* __restrict__ out_nd,
    int first)
{
    __shared__ float lds[2 * BUFSZ];
    const int tid = threadIdx.x;
    const int tx  = tid & 15;
    const int t4  = (tid >> 4) & 3;
    const int ocq = tid >> 6;                 // 0..3
    const int b   = blockIdx.x;
    const int r0  = blockIdx.y * TR;
    const int ocg = blockIdx.z;               // 0..3
    const int oc0 = __builtin_amdgcn_readfirstlane(ocg * 16 + ocq * 4);

    float acc[4][4];
#pragma unroll
    for (int o = 0; o < 4; ++o)
#pragma unroll
        for (int p = 0; p < 4; ++p) acc[o][p] = 0.f;

    if (!first) {                             // ry == 0 at t==0 -> conv is 0
        // staging mapping: 256 lanes = q16 x icl16, each lane 6 rows
        const int q   = tid & 15;
        const int icl = (tid >> 4) & 15;
        const float* gsrc = ry + ((size_t)b * CC + icl) * HW;
        float4 pf[6];

#pragma unroll
        for (int j = 0; j < 6; ++j) {
            int sr = r0 - 1 + j;
            pf[j] = make_float4(0.f, 0.f, 0.f, 0.f);
            if (sr >= 0 && sr < 64)
                pf[j] = *(const float4*)(gsrc + sr * 64 + 4 * q);
        }
        {
            float* dst = lds + icl * ICSTRIDE;
#pragma unroll
            for (int j = 0; j < 6; ++j) {
                float aw = __shfl_up(pf[j].w, 1, 16);
                if (q == 0) aw = 0.f;
                *(float4*)(dst + j * LDSROW + 4 * q) =
                    make_float4(aw, pf[j].x, pf[j].y, pf[j].z);
                if (q == 15)
                    *(float4*)(dst + j * LDSROW + 64) =
                        make_float4(pf[j].w, 0.f, 0.f, 0.f);
            }
        }
        __syncthreads();

#pragma unroll 1
        for (int ck = 0; ck < 4; ++ck) {
            if (ck < 3) {
                const float* g = gsrc + (size_t)(ck + 1) * CHUNK * HW;
#pragma unroll
                for (int j = 0; j < 6; ++j) {
                    int sr = r0 - 1 + j;
                    pf[j] = make_float4(0.f, 0.f, 0.f, 0.f);
                    if (sr >= 0 && sr < 64)
                        pf[j] = *(const float4*)(g + sr * 64 + 4 * q);
                }
            }
            const float* p  = lds + (ck & 1) * BUFSZ + t4 * LDSROW + 4 * tx;
            const float* wb = w_f + ((size_t)oc0 * CC + ck * CHUNK) * 9;

            float winA[3][6], winB[3][6];
            float wA[4][9], wB[4][9];
            load_win6(p, winA);
#pragma unroll
            for (int o = 0; o < 4; ++o) load_w9(wb + o * CC * 9, wA[o]);

#pragma unroll 1
            for (int ic2 = 0; ic2 < CHUNK; ic2 += 2) {
                load_win6(p + ICSTRIDE, winB);
#pragma unroll
                for (int o = 0; o < 4; ++o) load_w9(wb + 9 + o * CC * 9, wB[o]);

                fma36r(wA[0], winA, acc[0]);
                fma36r(wA[1], winA, acc[1]);
                fma36r(wA[2], winA, acc[2]);
                fma36r(wA[3], winA, acc[3]);

                if (ic2 + 2 < CHUNK) {
                    load_win6(p + 2 * ICSTRIDE, winA);
#pragma unroll
                    for (int o = 0; o < 4; ++o) load_w9(wb + 18 + o * CC * 9, wA[o]);
                }

                fma36r(wB[0], winB, acc[0]);
                fma36r(wB[1], winB, acc[1]);
                fma36r(wB[2], winB, acc[2]);
                fma36r(wB[3], winB, acc[3]);

                p  += 2 * ICSTRIDE;
                wb += 18;
            }
            if (ck < 3) {
                float* dst = lds + ((ck + 1) & 1) * BUFSZ + icl * ICSTRIDE;
#pragma unroll
                for (int j = 0; j < 6; ++j) {
                    float aw = __shfl_up(pf[j].w, 1, 16);
                    if (q == 0) aw = 0.f;
                    *(float4*)(dst + j * LDSROW + 4 * q) =
                        make_float4(aw, pf[j].x, pf[j].y, pf[j].z);
                    if (q == 15)
                        *(float4*)(dst + j * LDSROW + 64) =
                            make_float4(pf[j].w, 0.f, 0.f, 0.f);
                }
            }
            __syncthreads();
        }
    }

    // epilogue: GRU update + spike
    const int gr = r0 + t4;
    const size_t pix = (size_t)gr * 64 + 4 * tx;
    const float4 t4q = *(const float4*)(ws_thr + (size_t)b * HW + pix);
#pragma unroll
    for (int o = 0; o < 4; ++o) {
        int oc = oc0 + o;
        float bias = b_f[oc];
        const size_t coff = ((size_t)b * CC + oc) * HW + pix;
        const float4 x4 = *(const float4*)(xt_t + ((size_t)b * 192 + 2 * CC + oc) * HW + pix);
        const float4 u4 = *(const float4*)(ws_u + coff);
        float4 h4;
        if (first) { h4 = make_float4(0.f, 0.f, 0.f, 0.f); }
        else       { h4 = *(const float4*)(ws_h + coff); }

        float fx[4] = { acc[o][0] + bias + x4.x, acc[o][1] + bias + x4.y,
                        acc[o][2] + bias + x4.z, acc[o][3] + bias + x4.w };
        float uu[4] = { u4.x, u4.y, u4.z, u4.w };
        float hh[4] = { h4.x, h4.y, h4.z, h4.w };
        float tt[4] = { t4q.x, t4q.y, t4q.z, t4q.w };
        float yv[4], ev[4], nd[4], hc[4];
#pragma unroll
        for (int j = 0; j < 4; ++j) {
            float ig = tanhf(fx[j]);
            float hn = (1.f - uu[j]) * hh[j] + uu[j] * ig;
            float d  = hn - tt[j];
            bool pos = d > 0.f;
            ev[j] = pos ? 1.f : 0.f;
            yv[j] = pos ? hn : 0.f;
            nd[j] = (d < 0.f) ? (tt[j] - hn) : 0.f;
            hc[j] = pos ? (hn - tt[j]) : hn;
        }
        *(float4*)(out_y + coff)  = make_float4(yv[0], yv[1], yv[2], yv[3]);
        *(float4*)(out_e + coff)  = make_float4(ev[0], ev[1], ev[2], ev[3]);
        *(float4*)(out_nd + coff) = make_float4(nd[0], nd[1], nd[2], nd[3]);
        *(float4*)(ws_h + coff)   = make_float4(hc[0], hc[1], hc[2], hc[3]);
    }
}

extern "C" void kernel_launch(void* const* d_in, const int* in_sizes, int n_in,
                              void* d_out, int out_size, void* d_ws, size_t ws_size,
                              hipStream_t stream) {
    const float* xt   = (const float*)d_in[0];
    const float* w_rz = (const float*)d_in[1];
    const float* b_rz = (const float*)d_in[2];
    const float* w_f  = (const float*)d_in[3];
    const float* b_f  = (const float*)d_in[4];
    float* out = (float*)d_out;
    float* ws  = (float*)d_ws;

    const size_t NCHW = (size_t)NB * CC * HW;   // 1,048,576 floats
    float* ws_u   = ws;
    float* ws_ry  = ws + NCHW;
    float* ws_thr = ws + 2 * NCHW;
    float* ws_h   = ws + 2 * NCHW + (size_t)NB * HW;

    float* ys  = out;
    float* es  = out + (size_t)NT * NCHW;
    float* nds = out + 2 * (size_t)NT * NCHW;

    for (int t = 0; t < NT; ++t) {
        const float* xtt = xt + (size_t)t * NB * 192 * HW;
        const float* py  = (t == 0) ? xtt : (ys + (size_t)(t - 1) * NCHW);
        hipLaunchKernelGGL(convA_kernel, dim3(NB, 16, 4), dim3(512), 0, stream,
                           py, xtt, w_rz, b_rz, ws_u, ws_ry, ws_thr, (t == 0) ? 1 : 0);
        hipLaunchKernelGGL(convB_kernel, dim3(NB, 16, 4), dim3(256), 0, stream,
                           ws_ry, xtt, w_f, b_f, ws_u, ws_thr, ws_h,
                           ys + (size_t)t * NCHW, es + (size_t)t * NCHW,
                           nds + (size_t)t * NCHW, (t == 0) ? 1 : 0);
    }
}

// Round 4
// 921.649 us; speedup vs baseline: 1.7476x; 1.7476x over previous
//
#include <hip/hip_runtime.h>
#include <math.h>

#define CC 64
#define HW 4096
#define NB 4
#define NT 10
#define TR 4                     // output rows per block
#define CHUNK 16                 // input channels staged per chunk
#define LDSROW 68                // padded row width (col j = img col j-1)
#define ICSTRIDE (6*LDSROW)      // 408 floats per ic (6 rows)
#define BUFSZ (CHUNK*ICSTRIDE)   // 6528 floats per buffer

__device__ __forceinline__ float sigm(float x) { return 1.0f / (1.0f + expf(-x)); }

__device__ __forceinline__ void load_win6(const float* __restrict__ p, float (&w)[3][6]) {
#pragma unroll
    for (int dr = 0; dr < 3; ++dr) {
        float4 a  = *(const float4*)(p + dr * LDSROW);
        float2 e2 = *(const float2*)(p + dr * LDSROW + 4);
        w[dr][0] = a.x;  w[dr][1] = a.y;  w[dr][2] = a.z;
        w[dr][3] = a.w;  w[dr][4] = e2.x; w[dr][5] = e2.y;
    }
}

// Inline weight loads: pointer is wave-uniform -> s_load path, few live at a
// time (R3 lesson: staging weights to arrays overflows SGPRs -> VMEM -> 1.5x).
__device__ __forceinline__ void fma36(const float* __restrict__ w9,
                                      const float (&win)[3][6], float (&a)[4]) {
    float w0=w9[0],w1=w9[1],w2=w9[2],w3=w9[3],w4=w9[4];
    float w5=w9[5],w6=w9[6],w7=w9[7],w8=w9[8];
#pragma unroll
    for (int pp = 0; pp < 4; ++pp) {
        float s = a[pp];
        s = fmaf(w0, win[0][pp],   s);
        s = fmaf(w1, win[0][pp+1], s);
        s = fmaf(w2, win[0][pp+2], s);
        s = fmaf(w3, win[1][pp],   s);
        s = fmaf(w4, win[1][pp+1], s);
        s = fmaf(w5, win[1][pp+2], s);
        s = fmaf(w6, win[2][pp],   s);
        s = fmaf(w7, win[2][pp+1], s);
        s = fmaf(w8, win[2][pp+2], s);
        a[pp] = s;
    }
}

// ---------------------------------------------------------------------------
// Kernel A: rz = conv3x3(prev_y, w_rz) + b_rz (129 ch).
// 512 threads: tx16(4col) x t4(4row) x ocq8(4oc) -> 32 oc/block, 4 ocg blocks.
// thr (oc 128) folded into ocq==0 wave of ocg==0 blocks.
// Double-buffered LDS, reg-staged prefetch, 1 barrier per 16-ic chunk.
// ic loop: win (LDS) ping-pong only; weights inline (s_load path).
// ---------------------------------------------------------------------------
__global__ __launch_bounds__(512, 2) void convA_kernel(
    const float* __restrict__ prev_y,
    const float* __restrict__ xt_t,
    const float* __restrict__ w_rz,
    const float* __restrict__ b_rz,
    float* __restrict__ ws_u,
    float* __restrict__ ws_ry,
    float* __restrict__ ws_thr,
    int first)
{
    __shared__ float lds[2 * BUFSZ];
    const int tid = threadIdx.x;
    const int tx  = tid & 15;
    const int t4  = (tid >> 4) & 3;
    const int ocq = tid >> 6;                 // 0..7 == wave id
    const int b   = blockIdx.x;
    const int r0  = blockIdx.y * TR;
    const int ocg = blockIdx.z;               // 0..3
    const int oc0 = __builtin_amdgcn_readfirstlane(ocg * 32 + ocq * 4);
    const bool do_thr = (ocg == 0) && (ocq == 0);

    float acc[4][4];
#pragma unroll
    for (int o = 0; o < 4; ++o)
#pragma unroll
        for (int p = 0; p < 4; ++p) acc[o][p] = 0.f;
    float acct[4] = {0.f, 0.f, 0.f, 0.f};

    if (!first) {
        // staging mapping: 512 lanes = q16 x icl16 x rh2 (rows rh*3+0..2)
        const int q   = tid & 15;
        const int icl = (tid >> 4) & 15;
        const int rh  = tid >> 8;             // 0/1
        const float* gsrc = prev_y + ((size_t)b * CC + icl) * HW;
        float4 pf[3];

        // prologue: load + store chunk 0
#pragma unroll
        for (int j = 0; j < 3; ++j) {
            int sr = r0 - 1 + rh * 3 + j;
            pf[j] = make_float4(0.f, 0.f, 0.f, 0.f);
            if (sr >= 0 && sr < 64)
                pf[j] = *(const float4*)(gsrc + sr * 64 + 4 * q);
        }
        {
            float* dst = lds + icl * ICSTRIDE;
#pragma unroll
            for (int j = 0; j < 3; ++j) {
                int row = rh * 3 + j;
                float aw = __shfl_up(pf[j].w, 1, 16);
                if (q == 0) aw = 0.f;
                *(float4*)(dst + row * LDSROW + 4 * q) =
                    make_float4(aw, pf[j].x, pf[j].y, pf[j].z);
                if (q == 15)
                    *(float4*)(dst + row * LDSROW + 64) =
                        make_float4(pf[j].w, 0.f, 0.f, 0.f);
            }
        }
        __syncthreads();

#pragma unroll 1
        for (int ck = 0; ck < 4; ++ck) {
            // issue next chunk's global loads (hidden under compute)
            if (ck < 3) {
                const float* g = gsrc + (size_t)(ck + 1) * CHUNK * HW;
#pragma unroll
                for (int j = 0; j < 3; ++j) {
                    int sr = r0 - 1 + rh * 3 + j;
                    pf[j] = make_float4(0.f, 0.f, 0.f, 0.f);
                    if (sr >= 0 && sr < 64)
                        pf[j] = *(const float4*)(g + sr * 64 + 4 * q);
                }
            }
            const float* p  = lds + (ck & 1) * BUFSZ + t4 * LDSROW + 4 * tx;
            const float* wz = w_rz + ((size_t)oc0 * CC + ck * CHUNK) * 9;
            const float* wt = w_rz + ((size_t)128 * CC + ck * CHUNK) * 9;

            float winA[3][6], winB[3][6];
            load_win6(p, winA);
#pragma unroll 1
            for (int ic2 = 0; ic2 < CHUNK; ic2 += 2) {
                load_win6(p + ICSTRIDE, winB);        // ic2+1
                fma36(wz,              winA, acc[0]);
                fma36(wz + 1 * CC * 9, winA, acc[1]);
                fma36(wz + 2 * CC * 9, winA, acc[2]);
                fma36(wz + 3 * CC * 9, winA, acc[3]);
                if (do_thr) fma36(wt, winA, acct);
                if (ic2 + 2 < CHUNK)
                    load_win6(p + 2 * ICSTRIDE, winA); // ic2+2
                fma36(wz + 9,              winB, acc[0]);
                fma36(wz + 9 + 1 * CC * 9, winB, acc[1]);
                fma36(wz + 9 + 2 * CC * 9, winB, acc[2]);
                fma36(wz + 9 + 3 * CC * 9, winB, acc[3]);
                if (do_thr) fma36(wt + 9, winB, acct);
                p  += 2 * ICSTRIDE;
                wz += 18;
                wt += 18;
            }
            if (ck < 3) {
                float* dst = lds + ((ck + 1) & 1) * BUFSZ + icl * ICSTRIDE;
#pragma unroll
                for (int j = 0; j < 3; ++j) {
                    int row = rh * 3 + j;
                    float aw = __shfl_up(pf[j].w, 1, 16);
                    if (q == 0) aw = 0.f;
                    *(float4*)(dst + row * LDSROW + 4 * q) =
                        make_float4(aw, pf[j].x, pf[j].y, pf[j].z);
                    if (q == 15)
                        *(float4*)(dst + row * LDSROW + 64) =
                            make_float4(pf[j].w, 0.f, 0.f, 0.f);
                }
            }
            __syncthreads();
        }
    }

    // epilogue
    const int gr = r0 + t4;
    const size_t pix = (size_t)gr * 64 + 4 * tx;
    if (ocg < 2) {                            // z: update gate -> ws_u
#pragma unroll
        for (int o = 0; o < 4; ++o) {
            int oc = oc0 + o;
            float bias = b_rz[oc];
            const float4 x4 = *(const float4*)(xt_t + ((size_t)b * 192 + oc) * HW + pix);
            float4 outv;
            outv.x = sigm(acc[o][0] + bias + x4.x);
            outv.y = sigm(acc[o][1] + bias + x4.y);
            outv.z = sigm(acc[o][2] + bias + x4.z);
            outv.w = sigm(acc[o][3] + bias + x4.w);
            *(float4*)(ws_u + ((size_t)b * CC + oc) * HW + pix) = outv;
        }
    } else {                                  // r: ry = prev_y * reset_gate
#pragma unroll
        for (int o = 0; o < 4; ++o) {
            int oc = oc0 + o;
            int ch = oc - CC;
            float bias = b_rz[oc];
            const float4 x4 = *(const float4*)(xt_t + ((size_t)b * 192 + oc) * HW + pix);
            float4 py;
            if (first) { py = make_float4(0.f, 0.f, 0.f, 0.f); }
            else       { py = *(const float4*)(prev_y + ((size_t)b * CC + ch) * HW + pix); }
            float4 outv;
            outv.x = py.x * sigm(acc[o][0] + bias + x4.x);
            outv.y = py.y * sigm(acc[o][1] + bias + x4.y);
            outv.z = py.z * sigm(acc[o][2] + bias + x4.z);
            outv.w = py.w * sigm(acc[o][3] + bias + x4.w);
            *(float4*)(ws_ry + ((size_t)b * CC + ch) * HW + pix) = outv;
        }
    }
    if (do_thr) {
        float bias = b_rz[2 * CC];
        float4 outv;
        outv.x = sigm(acct[0] + bias);
        outv.y = sigm(acct[1] + bias);
        outv.z = sigm(acct[2] + bias);
        outv.w = sigm(acct[3] + bias);
        *(float4*)(ws_thr + (size_t)b * HW + pix) = outv;
    }
}

// ---------------------------------------------------------------------------
// Kernel B: f = conv3x3(ry, w_f) + b_f + xi_f ; fused GRU update + spike.
// Now 512 threads: tx16(4col) x t4(4row) x ocq8(2oc) -> 16 oc/block, 4 ocg.
// Grid 256 blocks = 1/CU, 2 waves/SIMD (was 1 at 256 threads) -> TLP covers
// the per-ic lgkmcnt stalls. win ping-pong + inline weights.
// ---------------------------------------------------------------------------
__global__ __launch_bounds__(512, 2) void convB_kernel(
    const float* __restrict__ ry,
    const float* __restrict__ xt_t,
    const float* __restrict__ w_f,
    const float* __restrict__ b_f,
    const float* __restrict__ ws_u,
    const float* __restrict__ ws_thr,
    float* __restrict__ ws_h,
    float* __restrict__ out_y,
    float* __restrict__ out_e,
    float* __restrict__ out_nd,
    int first)
{
    __shared__ float lds[2 * BUFSZ];
    const int tid = threadIdx.x;
    const int tx  = tid & 15;
    const int t4  = (tid >> 4) & 3;
    const int ocq = tid >> 6;                 // 0..7
    const int b   = blockIdx.x;
    const int r0  = blockIdx.y * TR;
    const int ocg = blockIdx.z;               // 0..3
    const int oc0 = __builtin_amdgcn_readfirstlane(ocg * 16 + ocq * 2);

    float acc[2][4];
#pragma unroll
    for (int o = 0; o < 2; ++o)
#pragma unroll
        for (int p = 0; p < 4; ++p) acc[o][p] = 0.f;

    if (!first) {                             // ry == 0 at t==0 -> conv is 0
        // staging mapping: 512 lanes = q16 x icl16 x rh2 (rows rh*3+0..2)
        const int q   = tid & 15;
        const int icl = (tid >> 4) & 15;
        const int rh  = tid >> 8;             // 0/1
        const float* gsrc = ry + ((size_t)b * CC + icl) * HW;
        float4 pf[3];

#pragma unroll
        for (int j = 0; j < 3; ++j) {
            int sr = r0 - 1 + rh * 3 + j;
            pf[j] = make_float4(0.f, 0.f, 0.f, 0.f);
            if (sr >= 0 && sr < 64)
                pf[j] = *(const float4*)(gsrc + sr * 64 + 4 * q);
        }
        {
            float* dst = lds + icl * ICSTRIDE;
#pragma unroll
            for (int j = 0; j < 3; ++j) {
                int row = rh * 3 + j;
                float aw = __shfl_up(pf[j].w, 1, 16);
                if (q == 0) aw = 0.f;
                *(float4*)(dst + row * LDSROW + 4 * q) =
                    make_float4(aw, pf[j].x, pf[j].y, pf[j].z);
                if (q == 15)
                    *(float4*)(dst + row * LDSROW + 64) =
                        make_float4(pf[j].w, 0.f, 0.f, 0.f);
            }
        }
        __syncthreads();

#pragma unroll 1
        for (int ck = 0; ck < 4; ++ck) {
            if (ck < 3) {
                const float* g = gsrc + (size_t)(ck + 1) * CHUNK * HW;
#pragma unroll
                for (int j = 0; j < 3; ++j) {
                    int sr = r0 - 1 + rh * 3 + j;
                    pf[j] = make_float4(0.f, 0.f, 0.f, 0.f);
                    if (sr >= 0 && sr < 64)
                        pf[j] = *(const float4*)(g + sr * 64 + 4 * q);
                }
            }
            const float* p  = lds + (ck & 1) * BUFSZ + t4 * LDSROW + 4 * tx;
            const float* wb = w_f + ((size_t)oc0 * CC + ck * CHUNK) * 9;

            float winA[3][6], winB[3][6];
            load_win6(p, winA);
#pragma unroll 1
            for (int ic2 = 0; ic2 < CHUNK; ic2 += 2) {
                load_win6(p + ICSTRIDE, winB);
                fma36(wb,          winA, acc[0]);
                fma36(wb + CC * 9, winA, acc[1]);
                if (ic2 + 2 < CHUNK)
                    load_win6(p + 2 * ICSTRIDE, winA);
                fma36(wb + 9,          winB, acc[0]);
                fma36(wb + 9 + CC * 9, winB, acc[1]);
                p  += 2 * ICSTRIDE;
                wb += 18;
            }
            if (ck < 3) {
                float* dst = lds + ((ck + 1) & 1) * BUFSZ + icl * ICSTRIDE;
#pragma unroll
                for (int j = 0; j < 3; ++j) {
                    int row = rh * 3 + j;
                    float aw = __shfl_up(pf[j].w, 1, 16);
                    if (q == 0) aw = 0.f;
                    *(float4*)(dst + row * LDSROW + 4 * q) =
                        make_float4(aw, pf[j].x, pf[j].y, pf[j].z);
                    if (q == 15)
                        *(float4*)(dst + row * LDSROW + 64) =
                            make_float4(pf[j].w, 0.f, 0.f, 0.f);
                }
            }
            __syncthreads();
        }
    }

    // epilogue: GRU update + spike (2 oc per thread)
    const int gr = r0 + t4;
    const size_t pix = (size_t)gr * 64 + 4 * tx;
    const float4 t4q = *(const float4*)(ws_thr + (size_t)b * HW + pix);
#pragma unroll
    for (int o = 0; o < 2; ++o) {
        int oc = oc0 + o;
        float bias = b_f[oc];
        const size_t coff = ((size_t)b * CC + oc) * HW + pix;
        const float4 x4 = *(const float4*)(xt_t + ((size_t)b * 192 + 2 * CC + oc) * HW + pix);
        const float4 u4 = *(const float4*)(ws_u + coff);
        float4 h4;
        if (first) { h4 = make_float4(0.f, 0.f, 0.f, 0.f); }
        else       { h4 = *(const float4*)(ws_h + coff); }

        float fx[4] = { acc[o][0] + bias + x4.x, acc[o][1] + bias + x4.y,
                        acc[o][2] + bias + x4.z, acc[o][3] + bias + x4.w };
        float uu[4] = { u4.x, u4.y, u4.z, u4.w };
        float hh[4] = { h4.x, h4.y, h4.z, h4.w };
        float tt[4] = { t4q.x, t4q.y, t4q.z, t4q.w };
        float yv[4], ev[4], nd[4], hc[4];
#pragma unroll
        for (int j = 0; j < 4; ++j) {
            float ig = tanhf(fx[j]);
            float hn = (1.f - uu[j]) * hh[j] + uu[j] * ig;
            float d  = hn - tt[j];
            bool pos = d > 0.f;
            ev[j] = pos ? 1.f : 0.f;
            yv[j] = pos ? hn : 0.f;
            nd[j] = (d < 0.f) ? (tt[j] - hn) : 0.f;
            hc[j] = pos ? (hn - tt[j]) : hn;
        }
        *(float4*)(out_y + coff)  = make_float4(yv[0], yv[1], yv[2], yv[3]);
        *(float4*)(out_e + coff)  = make_float4(ev[0], ev[1], ev[2], ev[3]);
        *(float4*)(out_nd + coff) = make_float4(nd[0], nd[1], nd[2], nd[3]);
        *(float4*)(ws_h + coff)   = make_float4(hc[0], hc[1], hc[2], hc[3]);
    }
}

extern "C" void kernel_launch(void* const* d_in, const int* in_sizes, int n_in,
                              void* d_out, int out_size, void* d_ws, size_t ws_size,
                              hipStream_t stream) {
    const float* xt   = (const float*)d_in[0];
    const float* w_rz = (const float*)d_in[1];
    const float* b_rz = (const float*)d_in[2];
    const float* w_f  = (const float*)d_in[3];
    const float* b_f  = (const float*)d_in[4];
    float* out = (float*)d_out;
    float* ws  = (float*)d_ws;

    const size_t NCHW = (size_t)NB * CC * HW;   // 1,048,576 floats
    float* ws_u   = ws;
    float* ws_ry  = ws + NCHW;
    float* ws_thr = ws + 2 * NCHW;
    float* ws_h   = ws + 2 * NCHW + (size_t)NB * HW;

    float* ys  = out;
    float* es  = out + (size_t)NT * NCHW;
    float* nds = out + 2 * (size_t)NT * NCHW;

    for (int t = 0; t < NT; ++t) {
        const float* xtt = xt + (size_t)t * NB * 192 * HW;
        const float* py  = (t == 0) ? xtt : (ys + (size_t)(t - 1) * NCHW);
        hipLaunchKernelGGL(convA_kernel, dim3(NB, 16, 4), dim3(512), 0, stream,
                           py, xtt, w_rz, b_rz, ws_u, ws_ry, ws_thr, (t == 0) ? 1 : 0);
        hipLaunchKernelGGL(convB_kernel, dim3(NB, 16, 4), dim3(512), 0, stream,
                           ws_ry, xtt, w_f, b_f, ws_u, ws_thr, ws_h,
                           ys + (size_t)t * NCHW, es + (size_t)t * NCHW,
                           nds + (size_t)t * NCHW, (t == 0) ? 1 : 0);
    }
}